// Round 7
// baseline (32.310 us; speedup 1.0000x reference)
//
#include <hip/hip_runtime.h>
#include <hip/hip_fp16.h>

#define NPTS 8192
#define KNN  15
#define WPB  8                // waves per block, 1 query per wave
#define TPB  (WPB * 64)       // 512 threads
#define SEG  64               // candidate buffer capacity per query

__device__ __forceinline__ int prefix_below(unsigned long long m) {
  return (int)__builtin_amdgcn_mbcnt_hi((unsigned int)(m >> 32),
            __builtin_amdgcn_mbcnt_lo((unsigned int)m, 0u));
}

// Packed fp16 min (ROCm header lacks __hmin2): single v_pk_min_f16.
__device__ __forceinline__ __half2 hmin2(__half2 a, __half2 b) {
  __half2 r;
  asm("v_pk_min_f16 %0, %1, %2" : "=v"(r) : "v"(a), "v"(b));
  return r;
}

// Ascending bitonic sort of one u32 per lane across a 64-lane wave.
__device__ __forceinline__ unsigned int bitonic_sort_u32(unsigned int v, int lane) {
#pragma unroll
  for (int k = 2; k <= 64; k <<= 1) {
#pragma unroll
    for (int j = k >> 1; j > 0; j >>= 1) {
      unsigned int o = __shfl_xor(v, j, 64);
      bool keep_min = ((lane & k) == 0) == ((lane & j) == 0);
      unsigned int lo = (v < o) ? v : o;
      unsigned int hi = (v < o) ? o : v;
      v = keep_min ? lo : hi;
    }
  }
  return v;
}

// Ascending bitonic sort of one u64 per lane across a 64-lane wave.
__device__ __forceinline__ unsigned long long bitonic_sort_u64(unsigned long long v, int lane) {
#pragma unroll
  for (int k = 2; k <= 64; k <<= 1) {
#pragma unroll
    for (int j = k >> 1; j > 0; j >>= 1) {
      unsigned long long o = __shfl_xor(v, j, 64);
      bool keep_min = ((lane & k) == 0) == ((lane & j) == 0);
      unsigned long long lo = (v < o) ? v : o;
      unsigned long long hi = (v < o) ? o : v;
      v = keep_min ? lo : hi;
    }
  }
  return v;
}

__global__ __launch_bounds__(TPB)   // no wave-min cap: avoid forced VGPR spills
void knn_kernel(const float* __restrict__ x, const int* __restrict__ y,
                float* __restrict__ out) {
  // sp layout: uint4 j = (xpair, ypair, xpair, ypair) covering points 4j..4j+3,
  // each pair is packed half2 of two consecutive points' coords.
  __shared__ __align__(16) unsigned int sp[NPTS];   // 32 KB fp16 screening copy
  __shared__ unsigned int ybits[NPTS / 32];         // 1 KB label bitset
  __shared__ unsigned int buf[WPB][SEG];            // 2 KB candidate indices

  const int tid = threadIdx.x;

  // ---- stage fp16-packed points and label bitset ----
  const float4* gx4 = (const float4*)x;             // pairs of points
#pragma unroll
  for (int i = tid; i < NPTS / 2; i += TPB) {
    float4 p = gx4[i];
    __half2 hx = __floats2half2_rn(p.x, p.z);
    __half2 hy = __floats2half2_rn(p.y, p.w);
    sp[2 * i]     = *(const unsigned int*)&hx;
    sp[2 * i + 1] = *(const unsigned int*)&hy;
  }
  if (tid < NPTS / 32) {
    const int4* yy = (const int4*)(y + (tid << 5));
    unsigned int b = 0;
#pragma unroll
    for (int k2 = 0; k2 < 8; ++k2) {
      int4 v = yy[k2];
      b |= ((unsigned int)(v.x & 1) << (4 * k2)) |
           ((unsigned int)(v.y & 1) << (4 * k2 + 1)) |
           ((unsigned int)(v.z & 1) << (4 * k2 + 2)) |
           ((unsigned int)(v.w & 1) << (4 * k2 + 3));
    }
    ybits[tid] = b;
  }
  __syncthreads();   // the only barrier; waves are independent below

  const int w = tid >> 6;
  const int lane = tid & 63;
  const int q = (int)blockIdx.x * WPB + w;
  const float2 xq = ((const float2*)x)[q];          // exact fp32 query coords
  const __half2 qx2 = __floats2half2_rn(xq.x, xq.x);  // same rounding as staged
  const __half2 qy2 = __floats2half2_rn(xq.y, xq.y);

  const uint4* sp4 = (const uint4*)sp;

  // ---- pass 1: per-lane fp16 min over 128-point stripe (self included, d=0) ----
  __half2 mm = __floats2half2_rn(6.0e4f, 6.0e4f);
#pragma unroll 4
  for (int s = 0; s < 32; ++s) {
    uint4 v = sp4[(s << 6) + lane];
    __half2 xa = *(const __half2*)&v.x, ya = *(const __half2*)&v.y;
    __half2 xb = *(const __half2*)&v.z, yb = *(const __half2*)&v.w;
    __half2 dxa = __hsub2(xa, qx2), dya = __hsub2(ya, qy2);
    __half2 dxb = __hsub2(xb, qx2), dyb = __hsub2(yb, qy2);
    __half2 da = __hfma2(dxa, dxa, __hmul2(dya, dya));
    __half2 db = __hfma2(dxb, dxb, __hmul2(dyb, dyb));
    mm = hmin2(mm, hmin2(da, db));
  }
  float m = fminf(__low2float(mm), __high2float(mm));

  // 16th-smallest lane-min: >=16 distinct points with fp16 d <= T, at most one
  // self => T upper-bounds the fp16 d of the true 16th point.
  unsigned int srt = bitonic_sort_u32(__float_as_uint(m), lane);
  const float T = __uint_as_float(__shfl(srt, KNN, 64));
  // Margin covering fp16<->fp64 discrepancy both ways (coord rounding ~2e-3 abs,
  // |dd| <= 2*e*(|dx|+|dy|) + e^2 + ulp terms), ~2x headroom:
  const float M = 0.035f * sqrtf(T) + 2.0e-4f + 0.01f * T;
  __half hTf = __float2half_rn(T + M);
  hTf = __ushort_as_half((unsigned short)(__half_as_ushort(hTf) + 2)); // round up 2 ulp
  const __half2 Tf2 = __half2half2(hTf);

  // ---- pass 2: collect indices with fp16 d <= Tf (bit-identical d to pass 1) ----
  int cnt = 0;
#pragma unroll 2
  for (int s = 0; s < 32; ++s) {
    uint4 v = sp4[(s << 6) + lane];
    __half2 xa = *(const __half2*)&v.x, ya = *(const __half2*)&v.y;
    __half2 xb = *(const __half2*)&v.z, yb = *(const __half2*)&v.w;
    __half2 dxa = __hsub2(xa, qx2), dya = __hsub2(ya, qy2);
    __half2 dxb = __hsub2(xb, qx2), dyb = __hsub2(yb, qy2);
    __half2 da = __hfma2(dxa, dxa, __hmul2(dya, dya));
    __half2 db = __hfma2(dxb, dxb, __hmul2(dyb, dyb));
    __half2 ta = __hsub2(Tf2, da);                 // sign clear <=> candidate
    __half2 tb = __hsub2(Tf2, db);
    unsigned int sa = *(const unsigned int*)&ta;
    unsigned int sb = *(const unsigned int*)&tb;
    if (__any((sa & sb & 0x80008000u) != 0x80008000u)) {  // any candidate in 256 pts
      int jb = ((s << 6) + lane) << 2;
      bool c0 = (sa & 0x00008000u) == 0;           // sign-bit tests, no cvt
      bool c1 = (sa & 0x80000000u) == 0;
      bool c2 = (sb & 0x00008000u) == 0;
      bool c3 = (sb & 0x80000000u) == 0;
      unsigned long long k0 = __ballot(c0);
      if (c0) { int o = cnt + prefix_below(k0); if (o < SEG) buf[w][o] = jb; }
      cnt += __popcll(k0);
      unsigned long long k1 = __ballot(c1);
      if (c1) { int o = cnt + prefix_below(k1); if (o < SEG) buf[w][o] = jb + 1; }
      cnt += __popcll(k1);
      unsigned long long k2 = __ballot(c2);
      if (c2) { int o = cnt + prefix_below(k2); if (o < SEG) buf[w][o] = jb + 2; }
      cnt += __popcll(k2);
      unsigned long long k3 = __ballot(c3);
      if (c3) { int o = cnt + prefix_below(k3); if (o < SEG) buf[w][o] = jb + 3; }
      cnt += __popcll(k3);
    }
  }

  // ---- final: exact fp64 keys from original fp32 coords, sort, vote ----
  int C = (cnt > SEG) ? SEG : cnt;                 // expected ~26, >=16 certified
  unsigned long long kv = ~0ull;
  if (lane < C) {
    int jj = (int)buf[w][lane];
    float2 pj = ((const float2*)x)[jj];
    double dx = (double)xq.x - (double)pj.x;       // exact fp32->fp64
    double dy = (double)xq.y - (double)pj.y;
    double dd = dx * dx + dy * dy;                 // rel err ~1e-16
    kv = ((unsigned long long)__double_as_longlong(dd) & ~0x1FFFull) |
         (unsigned long long)jj;                   // tie-break: lower index
    if (jj == q) kv = ~0ull;                       // drop self
  }
  kv = bitonic_sort_u64(kv, lane);
  int j15 = (int)(kv & 0x1FFFull);
  int lbl = (int)((ybits[j15 >> 5] >> (j15 & 31)) & 1u);
  unsigned long long vm = __ballot((lane < KNN) && lbl);
  if (lane == 0) out[q] = (__popcll(vm) >= 8) ? 1.0f : 0.0f;   // sum > 7.5
}

extern "C" void kernel_launch(void* const* d_in, const int* in_sizes, int n_in,
                              void* d_out, int out_size, void* d_ws, size_t ws_size,
                              hipStream_t stream) {
  const float* x = (const float*)d_in[0];
  const int* y = (const int*)d_in[1];
  float* out = (float*)d_out;
  dim3 grid(NPTS / WPB);   // 1024 blocks x 8 waves = 8192 waves (1 query each)
  dim3 block(TPB);
  hipLaunchKernelGGL(knn_kernel, grid, block, 0, stream, x, y, out);
}